// Round 19
// baseline (176.329 us; speedup 1.0000x reference)
//
#include <hip/hip_runtime.h>

#define KAPPA 0.95f

typedef __attribute__((ext_vector_type(8))) short short8;
typedef __attribute__((ext_vector_type(4))) float f32x4;
typedef __attribute__((ext_vector_type(2))) float f32x2;

// ---------- bf16 helpers ----------
static __device__ inline unsigned short f2bf(float f) {
    unsigned int u = __float_as_uint(f);
    unsigned int rounding = 0x7fffu + ((u >> 16) & 1u);
    u += rounding;
    return (unsigned short)(u >> 16);
}
static __device__ inline unsigned int pack2bf(float x, float y) {
    return (unsigned int)f2bf(x) | ((unsigned int)f2bf(y) << 16);
}

#define H_SCALE 4096.0f
#define BIN_CAP 10240
#define QCAP 8192

// ---------- 1. prep: blocks 0-127 proj row; 128-255 convw; 256 zeroes qcur ----------
__global__ __launch_bounds__(128) void prep_kernel(const float* __restrict__ W,
                                                   unsigned short* __restrict__ Wp_bf,
                                                   const float* __restrict__ Wm,
                                                   unsigned short* __restrict__ Wm_bf,
                                                   int* __restrict__ qcur) {
    const int tid = threadIdx.x;
    if (blockIdx.x == 256) {
        qcur[tid] = 0;
        qcur[tid + 128] = 0;
        qcur[tid + 256] = 0;
        qcur[tid + 384] = 0;
        return;
    }
    if (blockIdx.x >= 128) {
        const int b2 = blockIdx.x - 128;
        const int i0 = b2 * 256 + tid;
        Wm_bf[i0] = f2bf(Wm[i0]);
        Wm_bf[i0 + 128] = f2bf(Wm[i0 + 128]);
        return;
    }
    const int r = blockIdx.x;
    __shared__ float s[128];
    __shared__ float c[128];
    __shared__ int rho_s;

    const float w = W[r * 128 + tid];
    const float a = fabsf(w);
    s[tid] = a;
    if (tid == 0) rho_s = 0;
    __syncthreads();

    for (int k = 2; k <= 128; k <<= 1) {
        for (int j = k >> 1; j > 0; j >>= 1) {
            int ixj = tid ^ j;
            if (ixj > tid) {
                bool up = ((tid & k) == 0);
                float x = s[tid], y = s[ixj];
                if ((x > y) == up) { s[tid] = y; s[ixj] = x; }
            }
            __syncthreads();
        }
    }

    const float u = s[127 - tid];
    c[tid] = u;
    __syncthreads();
    for (int off = 1; off < 128; off <<= 1) {
        float add = (tid >= off) ? c[tid - off] : 0.f;
        __syncthreads();
        c[tid] += add;
        __syncthreads();
    }
    const float rowsum = c[127];
    const float css = c[tid] - KAPPA;
    if (u - css / (float)(tid + 1) > 0.f) atomicAdd(&rho_s, 1);
    __syncthreads();

    float out = w;
    if (rowsum > KAPPA) {
        int rho = max(rho_s, 1);
        float theta = (c[rho - 1] - KAPPA) / (float)rho;
        float m = fmaxf(a - theta, 0.f);
        out = (w > 0.f) ? m : ((w < 0.f) ? -m : 0.f);
    }
    Wp_bf[r * 128 + tid] = f2bf(out);  // row-major [c][k]
}

// ---------- 2. partition v3: one kernel, fixed per-bin queue regions ----------
__global__ __launch_bounds__(1024) void rpart_kernel(const int* __restrict__ src,
                                                     const int* __restrict__ dst,
                                                     int* __restrict__ qcur,
                                                     unsigned* __restrict__ queue2, int E,
                                                     unsigned N, int chunk) {
    __shared__ int cnt[512];
    __shared__ int ofs[512];
    __shared__ int cur[512];
    __shared__ int gbase[512];
    __shared__ unsigned stage[8192];  // >= chunk (6250)
    const int b = blockIdx.x;
    const int i0 = b * chunk;
    const int i1 = min(i0 + chunk, E);
    const int tid = threadIdx.x;
    if (tid < 512) cnt[tid] = 0;
    __syncthreads();
    for (int i = i0 + tid; i < i1; i += 1024) {
        unsigned g = ((unsigned)dst[i] * 512u) / N;
        atomicAdd(&cnt[g], 1);
    }
    __syncthreads();
    if (tid < 512) ofs[tid] = cnt[tid];
    __syncthreads();
    for (int off = 1; off < 512; off <<= 1) {
        int add = (tid < 512 && tid >= off) ? ofs[tid - off] : 0;
        __syncthreads();
        if (tid < 512) ofs[tid] += add;
        __syncthreads();
    }
    if (tid < 512) {
        int e = ofs[tid] - cnt[tid];
        ofs[tid] = e;
        cur[tid] = e;
        gbase[tid] = (cnt[tid] > 0) ? atomicAdd(&qcur[tid], cnt[tid]) : 0;
    }
    __syncthreads();
    for (int i = i0 + tid; i < i1; i += 1024) {
        unsigned d = (unsigned)dst[i];
        unsigned s = (unsigned)src[i];
        unsigned g = (d * 512u) / N;
        unsigned v0g = (g * N + 511u) >> 9;
        int p = atomicAdd(&cur[g], 1);
        stage[p] = ((d - v0g) << 24) | s;
    }
    __syncthreads();
    const int wid = tid >> 6, lane = tid & 63;
    for (int g = wid; g < 512; g += 16) {
        const int base = g * QCAP + gbase[g];
        const int o = ofs[g];
        const int c = cnt[g];
        for (int t = lane; t < c; t += 64) queue2[base + t] = stage[o + t];
    }
}

// ---------- 3. sub-bin counting sort -> PADDED csr + counts/cursor/dinv ----------
__global__ __launch_bounds__(1024) void subfill_kernel(const unsigned* __restrict__ queue2,
                                                       const int* __restrict__ qcur,
                                                       int* __restrict__ csr_src,
                                                       int* __restrict__ counts,
                                                       int* __restrict__ cursor,
                                                       float* __restrict__ dinv,
                                                       unsigned* __restrict__ h8z, unsigned N,
                                                       int E) {
    __shared__ int cnt[256];
    __shared__ int ofs[256];
    __shared__ int stage[BIN_CAP];
    const int B = blockIdx.x;
    const int g = (B & 7) * 64 + (B >> 3);
    const int e0 = g * QCAP;
    const int e1 = e0 + qcur[g];
    const unsigned v0 = ((unsigned)g * N + 511u) >> 9;
    const unsigned v1 = min((((unsigned)g + 1u) * N + 511u) >> 9, N);
    const int nn = (int)(v1 - v0);
    const int tid = threadIdx.x;
    if (g == 511 && tid < 32) h8z[(size_t)N * 32 + tid] = 0u;  // zeros row for sentinels
    if (tid < 256) cnt[tid] = 0;
    __syncthreads();
    for (int i = e0 + tid; i < e1; i += 1024) atomicAdd(&cnt[queue2[i] >> 24], 1);
    __syncthreads();
    int cp = 0;
    if (tid < 256) { cp = (cnt[tid] + 15) & ~15; ofs[tid] = cp; }
    __syncthreads();
    for (int off = 1; off < 256; off <<= 1) {
        int add = (tid < 256 && tid >= off) ? ofs[tid - off] : 0;
        __syncthreads();
        if (tid < 256) ofs[tid] += add;
        __syncthreads();
    }
    const int ptot = ofs[255];
    if (tid < nn) {
        int pexcl = ofs[tid] - cp;
        counts[v0 + tid] = cnt[tid];
        cursor[v0 + tid] = g * BIN_CAP + pexcl;
        dinv[v0 + tid] = rsqrtf((float)(cnt[tid] + 1));
    }
    __syncthreads();
    if (tid < 256) ofs[tid] -= cp;
    __syncthreads();
    const int sent = (int)(N * 8u);
    for (int t = tid; t < ptot; t += 1024) stage[t] = sent;
    __syncthreads();
    for (int i = e0 + tid; i < e1; i += 1024) {
        unsigned raw = queue2[i];
        int p = atomicAdd(&ofs[raw >> 24], 1);
        stage[p] = (int)((raw & 0xFFFFFFu) << 3);  // pre-scaled src*8
    }
    __syncthreads();
    for (int t = tid; t < ptot; t += 1024) csr_src[g * BIN_CAP + t] = stage[t];
}

// ---------- 4. MFMA GEMM (A=W, B=X): W staged per 128-K half (32KB LDS), ----------
// barriers only between halves. MODE 0: h8 = fp8(dinv*H_SCALE*acc);
// MODE 1: out = relu(acc + f32 ADD)
template <int KD, int MODE>
__global__ __launch_bounds__(512) void gemm_mfma(const float* __restrict__ X,
                                                 const unsigned short* __restrict__ Wbf,
                                                 const float* __restrict__ dinv,
                                                 const float* ADD,
                                                 unsigned int* __restrict__ out_u32,
                                                 float* out_f, int nrows) {
    constexpr int KH = 128;          // K-half staged at a time (32 KB)
    constexpr int NH = KD / KH;      // 1 (conv) or 2 (mlp)
    __shared__ __align__(16) unsigned short ldsW[128 * KH];
    const int tid = threadIdx.x;
    const int w = tid >> 6;
    const int l = tid & 63;
    const int l16 = l & 15;
    const int kg = l >> 4;
    const unsigned swz = (unsigned)((l16 & 7) << 4);  // lane-constant XOR swizzle
    const int row0 = blockIdx.x * 128;
    const int row = row0 + w * 16 + l16;
    const int rload = min(row, nrows - 1);
    const float* xrow = X + (size_t)rload * KD + kg * 8;

    f32x4 acc[8];
#pragma unroll
    for (int j = 0; j < 8; ++j) acc[j] = (f32x4)(0.f);

    char* lb = reinterpret_cast<char*>(ldsW);
    const char* lbr = reinterpret_cast<const char*>(ldsW);
    const uint4* wsrc = reinterpret_cast<const uint4*>(Wbf);

#pragma unroll
    for (int h = 0; h < NH; ++h) {
        if (h > 0) __syncthreads();  // protect previous half's reads
        // stage this K-half of W (swizzled): 128*KH/8 = 2048 uint4, 4/thread
#pragma unroll
        for (int i = 0; i < (128 * KH / 8) / 512; ++i) {
            int idx = i * 512 + tid;
            int c = idx >> 4;           // KH/8 == 16 chunks per row
            int kk8 = (idx & 15) * 8;
            unsigned byte = (unsigned)((c * KH + kk8) * 2) ^ (unsigned)((c & 7) << 4);
            *reinterpret_cast<uint4*>(lb + byte) = wsrc[(c * KD + h * KH + kk8) >> 3];
        }
        __syncthreads();

#pragma unroll
        for (int t = 0; t < KH / 32; ++t) {
            const float4 v0 = *reinterpret_cast<const float4*>(xrow + h * KH + t * 32);
            const float4 v1 = *reinterpret_cast<const float4*>(xrow + h * KH + t * 32 + 4);
            union { uint4 u; short8 s; } cvt;
            cvt.u.x = pack2bf(v0.x, v0.y);
            cvt.u.y = pack2bf(v0.z, v0.w);
            cvt.u.z = pack2bf(v1.x, v1.y);
            cvt.u.w = pack2bf(v1.z, v1.w);
            const short8 a = cvt.s;
#pragma unroll
            for (int ct = 0; ct < 8; ++ct) {
                const int c = ct * 16 + l16;
                unsigned byte = (unsigned)((c * KH + t * 32 + kg * 8) * 2) ^ swz;
                short8 wv = *reinterpret_cast<const short8*>(lbr + byte);
                acc[ct] = __builtin_amdgcn_mfma_f32_16x16x32_bf16(wv, a, acc[ct], 0, 0, 0);
            }
        }
    }

    // epilogue: lane's row; cols ct*16 + kg*4 + reg
    if (row < nrows) {
        if (MODE == 0) {
            const float dv = dinv[row] * H_SCALE;
#pragma unroll
            for (int ct = 0; ct < 8; ++ct) {
                f32x4 d = acc[ct];
                unsigned lo = __builtin_amdgcn_cvt_pk_fp8_f32(d[0] * dv, d[1] * dv, 0u, false);
                unsigned hi = __builtin_amdgcn_cvt_pk_fp8_f32(d[2] * dv, d[3] * dv, lo, true);
                out_u32[(size_t)row * 32 + ct * 4 + kg] = hi;
            }
        } else {
#pragma unroll
            for (int ct = 0; ct < 8; ++ct) {
                f32x4 d = acc[ct];
                const float4 a =
                    *reinterpret_cast<const float4*>(&ADD[(size_t)row * 128 + ct * 16 + kg * 4]);
                float4 o;
                o.x = fmaxf(d[0] + a.x, 0.f);
                o.y = fmaxf(d[1] + a.y, 0.f);
                o.z = fmaxf(d[2] + a.z, 0.f);
                o.w = fmaxf(d[3] + a.w, 0.f);
                *reinterpret_cast<float4*>(&out_f[(size_t)row * 128 + ct * 16 + kg * 4]) = o;
            }
        }
    }
}

// ---------- 5. aggregation over fp8 h': padded CSR, predicate-free, f32 out ----------
static __device__ inline void unp8v(f32x2* acc, unsigned wv, int off) {
    acc[off + 0] += __builtin_amdgcn_cvt_pk_f32_fp8(wv, false);
    acc[off + 1] += __builtin_amdgcn_cvt_pk_f32_fp8(wv, true);
}
static __device__ inline void unp16(f32x2* acc, uint4 val) {
    unp8v(acc, val.x, 0);
    unp8v(acc, val.y, 2);
    unp8v(acc, val.z, 4);
    unp8v(acc, val.w, 6);
}

__global__ __launch_bounds__(256) void agg_kernel(const uint4* __restrict__ h8,
                                                  const int* __restrict__ csr_src,
                                                  const int* __restrict__ cursor,
                                                  const int* __restrict__ counts,
                                                  const float* __restrict__ dinv,
                                                  float* __restrict__ agg, int n) {
    int v = blockIdx.x * 4 + (threadIdx.x >> 6);
    if (v >= n) return;
    const int lane = threadIdx.x & 63;
    const int eg = lane >> 3;  // 8 edge slots
    const int c = lane & 7;    // 16 features each (one uint4 of fp8)
    const int cnt = counts[v];
    const int start = cursor[v];
    const int cnt_pad = (cnt + 15) & ~15;

    f32x2 acc[8];
#pragma unroll
    for (int j = 0; j < 8; ++j) acc[j] = (f32x2)(0.f);

    int s0 = csr_src[start + eg];
    int s1 = csr_src[start + 8 + eg];
    for (int base = 0; base < cnt_pad; base += 16) {
        int t0 = s0, t1 = s1;
        s0 = csr_src[start + base + 16 + eg];
        s1 = csr_src[start + base + 24 + eg];
        uint4 va = h8[t0 + c];
        uint4 vb = h8[t1 + c];
        unp16(acc, va);
        unp16(acc, vb);
    }
    {  // self loop
        uint4 val = h8[(size_t)v * 8 + c];
        unp16(acc, val);
    }
#pragma unroll
    for (int j = 0; j < 8; ++j) {
#pragma unroll
        for (int k = 0; k < 2; ++k) {
            acc[j][k] += __shfl_xor(acc[j][k], 8);
            acc[j][k] += __shfl_xor(acc[j][k], 16);
            acc[j][k] += __shfl_xor(acc[j][k], 32);
        }
    }
    if (eg == 0) {
        const float dv = dinv[v] * (1.0f / H_SCALE);
#pragma unroll
        for (int k = 0; k < 4; ++k) {
            float4 o = {acc[2 * k][0] * dv, acc[2 * k][1] * dv, acc[2 * k + 1][0] * dv,
                        acc[2 * k + 1][1] * dv};
            *reinterpret_cast<float4*>(&agg[(size_t)v * 128 + c * 16 + k * 4]) = o;
        }
    }
}

// ---------- launch ----------
extern "C" void kernel_launch(void* const* d_in, const int* in_sizes, int n_in,
                              void* d_out, int out_size, void* d_ws, size_t ws_size,
                              hipStream_t stream) {
    const float* features = (const float*)d_in[0];
    const int*   edge     = (const int*)d_in[1];
    const float* emb      = (const float*)d_in[2];
    const float* Wconv    = (const float*)d_in[3];
    const float* Wmlp     = (const float*)d_in[4];
    float* out = (float*)d_out;

    const int N = in_sizes[0] / 256;
    const int E = in_sizes[1] / 2;
    const int* src = edge;
    const int* dst = edge + E;
    const int chunk = (E + 511) / 512;

    char* ws = (char*)d_ws;
    size_t o = 0;
    auto take = [&](size_t b) {
        size_t cur = o;
        o += (b + 255) & ~(size_t)255;
        return cur;
    };
    unsigned short* Wp_bf   = (unsigned short*)(ws + take((size_t)128 * 128 * 2));
    unsigned short* Wm_bf   = (unsigned short*)(ws + take((size_t)128 * 256 * 2));
    int*            counts  = (int*)(ws + take((size_t)N * 4));
    int*            cursor  = (int*)(ws + take((size_t)N * 4));
    float*          dinv    = (float*)(ws + take((size_t)N * 4));
    int*            qcur    = (int*)(ws + take((size_t)512 * 4));
    int*            csr_src = (int*)(ws + take((size_t)512 * BIN_CAP * 4 + 256));  // +slack
    size_t qbytes = (size_t)512 * QCAP * 4;
    size_t hbytes = (size_t)(N + 1) * 128;
    char*  qh     = ws + take(qbytes > hbytes ? qbytes : hbytes);
    unsigned*     queue2 = (unsigned*)qh;
    unsigned int* h8     = (unsigned int*)qh;
    (void)ws_size; (void)n_in; (void)out_size;

    hipLaunchKernelGGL(prep_kernel, dim3(257), dim3(128), 0, stream, Wconv, Wp_bf, Wmlp, Wm_bf,
                       qcur);
    hipLaunchKernelGGL(rpart_kernel, dim3(512), dim3(1024), 0, stream, src, dst, qcur, queue2, E,
                       (unsigned)N, chunk);
    hipLaunchKernelGGL(subfill_kernel, dim3(512), dim3(1024), 0, stream, queue2, qcur, csr_src,
                       counts, cursor, dinv, h8, (unsigned)N, E);
    // h8 = fp8( dinv[row]*4096 * (emb @ Wp.T) )  -- overwrites queue2 storage
    hipLaunchKernelGGL((gemm_mfma<128, 0>), dim3((N + 127) / 128), dim3(512), 0, stream, emb,
                       Wp_bf, dinv, (const float*)nullptr, h8, (float*)nullptr, N);
    hipLaunchKernelGGL(agg_kernel, dim3((N + 3) / 4), dim3(256), 0, stream, (const uint4*)h8,
                       csr_src, cursor, counts, dinv, out, N);
    // out = relu(features @ Wmlp.T + agg)
    hipLaunchKernelGGL((gemm_mfma<256, 1>), dim3((N + 127) / 128), dim3(512), 0, stream, features,
                       Wm_bf, (const float*)nullptr, out, (unsigned int*)nullptr, out, N);
}